// Round 12
// baseline (44.557 us; speedup 1.0000x reference)
//
#include <hip/hip_runtime.h>
#include <math.h>

#define H 64
#define W 64
#define C 256
#define NB 2
#define SS 32
#define HW (H*W)

typedef __attribute__((ext_vector_type(8))) _Float16 half8;
typedef __attribute__((ext_vector_type(2))) _Float16 half2v;

// ---- fmat body (fp64) ----
__device__ void fmat_compute(const float* __restrict__ P1f,
                             const float* __restrict__ P2f,
                             double* __restrict__ Fout, int n) {
  double p1[3][4], p2[3][4];
  for (int i = 0; i < 3; ++i)
    for (int j = 0; j < 4; ++j) {
      p1[i][j] = (double)P1f[n * 12 + i * 4 + j];
      p2[i][j] = (double)P2f[n * 12 + i * 4 + j];
    }
  double A[3][3];
  for (int i = 0; i < 3; ++i)
    for (int j = 0; j < 3; ++j) {
      double s = 0;
      for (int k = 0; k < 4; ++k) s += p1[i][k] * p1[j][k];
      A[i][j] = s;
    }
  double det = A[0][0] * (A[1][1] * A[2][2] - A[1][2] * A[2][1])
             - A[0][1] * (A[1][0] * A[2][2] - A[1][2] * A[2][0])
             + A[0][2] * (A[1][0] * A[2][1] - A[1][1] * A[2][0]);
  double id = 1.0 / det;
  double Ai[3][3];
  Ai[0][0] = (A[1][1] * A[2][2] - A[1][2] * A[2][1]) * id;
  Ai[0][1] = (A[0][2] * A[2][1] - A[0][1] * A[2][2]) * id;
  Ai[0][2] = (A[0][1] * A[1][2] - A[0][2] * A[1][1]) * id;
  Ai[1][0] = (A[1][2] * A[2][0] - A[1][0] * A[2][2]) * id;
  Ai[1][1] = (A[0][0] * A[2][2] - A[0][2] * A[2][0]) * id;
  Ai[1][2] = (A[0][2] * A[1][0] - A[0][0] * A[1][2]) * id;
  Ai[2][0] = (A[1][0] * A[2][1] - A[1][1] * A[2][0]) * id;
  Ai[2][1] = (A[0][1] * A[2][0] - A[0][0] * A[2][1]) * id;
  Ai[2][2] = (A[0][0] * A[1][1] - A[0][1] * A[1][0]) * id;
  double Pi[4][3];
  for (int i = 0; i < 4; ++i)
    for (int j = 0; j < 3; ++j) {
      double s = 0;
      for (int k = 0; k < 3; ++k) s += p1[k][i] * Ai[k][j];
      Pi[i][j] = s;
    }
  double M[3][3];
  for (int i = 0; i < 3; ++i)
    for (int j = 0; j < 3; ++j) {
      double s = 0;
      for (int k = 0; k < 4; ++k) s += p2[i][k] * Pi[k][j];
      M[i][j] = s;
    }
  double nv[4];
  {
    auto det3 = [&](int ca, int cb, int cc) {
      return p1[0][ca] * (p1[1][cb] * p1[2][cc] - p1[1][cc] * p1[2][cb])
           - p1[0][cb] * (p1[1][ca] * p1[2][cc] - p1[1][cc] * p1[2][ca])
           + p1[0][cc] * (p1[1][ca] * p1[2][cb] - p1[1][cb] * p1[2][ca]);
    };
    nv[0] =  det3(1, 2, 3);
    nv[1] = -det3(0, 2, 3);
    nv[2] =  det3(0, 1, 3);
    nv[3] = -det3(0, 1, 2);
  }
  double nn = sqrt(nv[0]*nv[0] + nv[1]*nv[1] + nv[2]*nv[2] + nv[3]*nv[3]);
  for (int i = 0; i < 4; ++i) nv[i] /= nn;
  double e2[3];
  for (int i = 0; i < 3; ++i) {
    double s = 0;
    for (int j = 0; j < 4; ++j) s += p2[i][j] * nv[j];
    e2[i] = s;
  }
  for (int j = 0; j < 3; ++j) {
    Fout[n * 9 + 0 * 3 + j] = -e2[2] * M[1][j] + e2[1] * M[2][j];
    Fout[n * 9 + 1 * 3 + j] =  e2[2] * M[0][j] - e2[0] * M[2][j];
    Fout[n * 9 + 2 * 3 + j] = -e2[1] * M[0][j] + e2[0] * M[1][j];
  }
}

// ---- Kernel 1: feat2 [N,C,H,W] -> f2t fp16 [N,HW,C]; fused fmat ------------
__global__ __launch_bounds__(256) void prep_kernel(
    const float* __restrict__ feat2,
    const float* __restrict__ P1f, const float* __restrict__ P2f,
    _Float16* __restrict__ f2t, double* __restrict__ Fd) {
  __shared__ float tile[32][33];
  const int n  = blockIdx.z;
  const int p0 = blockIdx.x * 32;
  const int c0 = blockIdx.y * 32;
  const int tx = threadIdx.x, ty = threadIdx.y;   // block (32,8)
  const float* src = feat2 + (size_t)n * (C * HW);
#pragma unroll
  for (int j = 0; j < 4; ++j) {
    int cc = c0 + ty + j * 8;
    tile[ty + j * 8][tx] = src[(size_t)cc * HW + p0 + tx];
  }
  __syncthreads();
  {
    const int tid = ty * 32 + tx;
    const int pp = tid >> 3;        // 0..31
    const int cp = tid & 7;         // 0..7
    _Float16* dst = f2t + (size_t)n * (HW * C) + (size_t)(p0 + pp) * C + c0;
#pragma unroll
    for (int jj = 0; jj < 2; ++jj) {
      const int cc = (cp + jj * 8) * 2;          // 0,2,..,30
      half2v h2;
      h2.x = (_Float16)tile[cc][pp];
      h2.y = (_Float16)tile[cc + 1][pp];
      *(half2v*)(dst + cc) = h2;
    }
  }
  if (n == 0 && blockIdx.x == 0 && blockIdx.y == 0) {
    int t = ty * 32 + tx;
    if (t < NB) fmat_compute(P1f, P2f, Fd, t);
  }
}

// ---- Kernel 2: per-(n,pixel,sample) gather records -------------------------
// rec = {o00 (element offset, bit0 = dy), o01, pack(w00,w01), pack(w10,w11)}
__global__ __launch_bounds__(256) void rec_kernel(
    const double* __restrict__ Fd, uint4* __restrict__ recs) {
  const int idx = blockIdx.x * 256 + threadIdx.x;   // (n,p,s)
  const int s = idx & 31;
  const int p = (idx >> 5) & (HW - 1);
  const int n = idx >> 17;
  const int h = p >> 6, w = p & (W - 1);

  // --- epipolar line + endpoint pick, fp32 (identical math to R9) ---
  const double* Fdp = Fd + n * 9;
  const float F0 = (float)Fdp[0], F1 = (float)Fdp[1], F2 = (float)Fdp[2];
  const float F3 = (float)Fdp[3], F4 = (float)Fdp[4], F5 = (float)Fdp[5];
  const float F6 = (float)Fdp[6], F7 = (float)Fdp[7], F8 = (float)Fdp[8];
  const float X = w * 4.0f + 1.5f;
  const float Y = h * 4.0f + 1.5f;
  const float a = F0 * X + F1 * Y + F2;
  const float b = F3 * X + F4 * Y + F5;
  const float c = F6 * X + F7 * Y + F8;
  const float a_s = (fabsf(a) < 1e-3f) ? 1e-3f : a;
  const float b_s = (fabsf(b) < 1e-3f) ? 1e-3f : b;
  const float xmin = 1.5f, xmax = 253.5f, ymin = 1.5f, ymax = 253.5f, tol = 0.01f;
  float cx[4], cy[4];
  cx[0] = xmin;  cy[0] = -(c + a * xmin) / b_s;
  cx[1] = xmax;  cy[1] = -(c + a * xmax) / b_s;
  cx[2] = -(c + b * ymin) / a_s;  cy[2] = ymin;
  cx[3] = -(c + b * ymax) / a_s;  cy[3] = ymax;
  bool valid[4];
#pragma unroll
  for (int i = 0; i < 4; ++i)
    valid[i] = (cx[i] >= xmin - tol) && (cx[i] <= xmax + tol) &&
               (cy[i] >= ymin - tol) && (cy[i] <= ymax + tol);
#pragma unroll
  for (int i = 0; i < 4; ++i)
    if (!valid[i]) { cx[i] = xmin - 10000.0f; cy[i] = ymin - 10000.0f; }
  int pk0 = -1, pk1 = -1;
#pragma unroll
  for (int i = 0; i < 4; ++i)
    if (valid[i]) { if (pk0 < 0) pk0 = i; else if (pk1 < 0) pk1 = i; }
#pragma unroll
  for (int i = 0; i < 4; ++i)
    if (!valid[i]) { if (pk0 < 0) pk0 = i; else if (pk1 < 0) pk1 = i; }
  const float x0p = (cx[pk0] - 1.5f) * 0.25f;
  const float y0p = (cy[pk0] - 1.5f) * 0.25f;
  const float pdx = (cx[pk1] - 1.5f) * 0.25f - x0p;
  const float pdy = (cy[pk1] - 1.5f) * 0.25f - y0p;

  const float t = (float)s * (1.0f / 31.0f);
  const float x = fmaf(t, pdx, x0p);
  const float y = fmaf(t, pdy, y0p);
  const float xf = floorf(x), yf = floorf(y);
  const float wx = x - xf, wy = y - yf;
  const int x0 = (int)xf, y0 = (int)yf;
  const bool bx0 = ((unsigned)x0 < W), bx1 = ((unsigned)(x0 + 1) < W);
  const bool by0 = ((unsigned)y0 < H), by1 = ((unsigned)(y0 + 1) < H);
  const int xc0 = min(max(x0, 0), W - 1);
  const int xc1 = min(max(x0 + 1, 0), W - 1);
  const int yc0 = min(max(y0, 0), H - 1);
  const int yc1 = min(max(y0 + 1, 0), H - 1);
  const float u0 = 1.f - wx, v0 = 1.f - wy;
  const _Float16 w00 = (_Float16)(v0 * u0 * (float)(bx0 & by0));
  const _Float16 w01 = (_Float16)(v0 * wx * (float)(bx1 & by0));
  const _Float16 w10 = (_Float16)(wy * u0 * (float)(bx0 & by1));
  const _Float16 w11 = (_Float16)(wy * wx * (float)(bx1 & by1));

  uint4 rc;
  rc.x = (uint)((yc0 * W + xc0) * C) | (uint)(yc1 - yc0);   // dy in bit0
  rc.y = (uint)((yc0 * W + xc1) * C);
  rc.z = ((uint)__builtin_bit_cast(unsigned short, w01) << 16) |
          (uint)__builtin_bit_cast(unsigned short, w00);
  rc.w = ((uint)__builtin_bit_cast(unsigned short, w11) << 16) |
          (uint)__builtin_bit_cast(unsigned short, w10);
  recs[idx] = rc;
}

// ---- 32-lane-group sum: 4 DPP steps (VALU) + 1 ds_swizzle (xor16) ----------
__device__ __forceinline__ float groupsum32(float v) {
  v += __int_as_float(__builtin_amdgcn_update_dpp(
         0, __float_as_int(v), 0xB1, 0xF, 0xF, true));   // quad_perm xor1
  v += __int_as_float(__builtin_amdgcn_update_dpp(
         0, __float_as_int(v), 0x4E, 0xF, 0xF, true));   // quad_perm xor2
  v += __int_as_float(__builtin_amdgcn_update_dpp(
         0, __float_as_int(v), 0x124, 0xF, 0xF, true));  // row_ror:4
  v += __int_as_float(__builtin_amdgcn_update_dpp(
         0, __float_as_int(v), 0x128, 0xF, 0xF, true));  // row_ror:8
  v += __int_as_float(__builtin_amdgcn_ds_swizzle(
         __float_as_int(v), 0x401F));                    // xor16
  return v;
}

// ---- Kernel 3: 2 px/wave, 32 lanes/px, 8 ch/lane; record-driven gathers ----
// Pipeline: rec fetched 3 ahead, corners issued 2 ahead, process current.
// XCD pinning: bid%8 = XCD -> (image n, row stripe sub).
struct Stage {
  half8 a, b, c, d;
  _Float16 w00, w01, w10, w11;
};

__global__ __launch_bounds__(256) void epi_main(
    const float* __restrict__ feat1, const _Float16* __restrict__ f2t,
    const uint4* __restrict__ recs, float* __restrict__ out) {
  const int tid  = threadIdx.x;
  const int lane = tid & 63;
  const int wv   = tid >> 6;
  const int grp  = lane >> 5;               // pixel within wave (0/1)
  const int cl   = lane & 31;               // channel lane
  const int bid  = blockIdx.x;
  const int r    = bid & 7;
  const int k    = bid >> 3;                // 0..127
  const int n    = r >> 2;
  const int sub  = r & 3;                   // row stripe
  const int p    = (sub * 128 + k) * 8 + wv * 2 + grp;
  const int cb = cl * 8;                    // channel base for this lane

  // --- f1: 8 channels cb..cb+7 straight from [N,C,H,W] (read once) ---
  float f1r[8];
  {
    const float* f1b = feat1 + ((size_t)n * C + cb) * HW + p;
#pragma unroll
    for (int i = 0; i < 8; ++i) f1r[i] = f1b[(size_t)i * HW];
  }

  const _Float16* f2b = f2t + (size_t)n * HW * C + cb;
  const uint4* recp = recs + (((size_t)n * HW + p) << 5);

  float m = -1e30f, l = 0.f;
  float acc[8];
#pragma unroll
  for (int i = 0; i < 8; ++i) acc[i] = 0.f;

  auto loadrec = [&](int s, uint4& rc) {
    rc = recp[min(s, SS - 1)];
  };

  // decode record + issue 4 corner loads (no use of results here)
  auto corner = [&](const uint4& rc, Stage& st) {
    const uint dy = rc.x & 1u;
    const _Float16* pa = f2b + (rc.x ^ dy);
    const _Float16* pb = f2b + rc.y;
    const uint d14 = dy << 14;               // dy * W * C elements
    st.a = *(const half8*)pa;
    st.b = *(const half8*)pb;
    st.c = *(const half8*)(pa + d14);
    st.d = *(const half8*)(pb + d14);
    const half2v wx = __builtin_bit_cast(half2v, rc.z);
    const half2v wy = __builtin_bit_cast(half2v, rc.w);
    st.w00 = wx.x; st.w01 = wx.y; st.w10 = wy.x; st.w11 = wy.y;
  };

  auto process = [&](const Stage& st) {
    half8 qh = st.a * st.w00 + st.b * st.w01 + st.c * st.w10 + st.d * st.w11;
    float part = 0.f;
#pragma unroll
    for (int i = 0; i < 8; ++i) part = fmaf(f1r[i], (float)qh[i], part);
    part = groupsum32(part);

    if (__any(part > m + 8.f)) {          // defer-max, wave-uniform
      const float mn = fmaxf(m, part);
      const float sc = __expf(m - mn);
      l *= sc;
#pragma unroll
      for (int i = 0; i < 8; ++i) acc[i] *= sc;
      m = mn;
    }
    const float e = __expf(part - m);
    l += e;
#pragma unroll
    for (int i = 0; i < 8; ++i) acc[i] = fmaf(e, (float)qh[i], acc[i]);
  };

  // schedule: rec 3 ahead, corners 2 ahead, process current; 3-slot rotation
  uint4 r0_, r1_, r2_;
  Stage s0_, s1_, s2_;
  loadrec(0, r0_); loadrec(1, r1_); loadrec(2, r2_);
  corner(r0_, s0_); corner(r1_, s1_);
  for (int j = 0; j < 30; j += 3) {
    loadrec(j + 3, r0_);
    corner(r2_, s2_);          // sample j+2
    process(s0_);              // sample j
    loadrec(j + 4, r1_);
    corner(r0_, s0_);          // sample j+3
    process(s1_);              // sample j+1
    loadrec(j + 5, r2_);
    corner(r1_, s1_);          // sample j+4
    process(s2_);              // sample j+2
  }
  process(s0_);   // sample 30
  process(s1_);   // sample 31

  const float inv = 1.0f / l;
  float* ob = out + (size_t)n * C * HW + (size_t)cb * HW + p;
#pragma unroll
  for (int i = 0; i < 8; ++i) ob[(size_t)i * HW] = acc[i] * inv;
}

extern "C" void kernel_launch(void* const* d_in, const int* in_sizes, int n_in,
                              void* d_out, int out_size, void* d_ws, size_t ws_size,
                              hipStream_t stream) {
  const float* feat1 = (const float*)d_in[0];
  const float* feat2 = (const float*)d_in[1];
  const float* P1 = (const float*)d_in[2];
  const float* P2 = (const float*)d_in[3];
  float* out = (float*)d_out;

  char* ws = (char*)d_ws;
  _Float16* f2t = (_Float16*)ws;                            // 4 MB @ 0
  double*   Fd  = (double*)(ws + (5u << 20));               // @ 5 MB
  uint4*    recs = (uint4*)(ws + (6u << 20));               // 4 MB @ 6 MB

  prep_kernel<<<dim3(HW / 32, C / 32, NB), dim3(32, 8), 0, stream>>>(
      feat2, P1, P2, f2t, Fd);
  rec_kernel<<<NB * HW * SS / 256, 256, 0, stream>>>(Fd, recs);
  epi_main<<<NB * HW / 8, 256, 0, stream>>>(feat1, f2t, recs, out);
}

// Round 14
// 40.674 us; speedup vs baseline: 1.0955x; 1.0955x over previous
//
#include <hip/hip_runtime.h>
#include <math.h>

#define H 64
#define W 64
#define C 256
#define NB 2
#define SS 32
#define HW (H*W)

typedef __attribute__((ext_vector_type(2))) _Float16 half2v;

// cvt_pkrtz returns an __fp16 vector; bit-cast to our half2v (same layout)
__device__ __forceinline__ half2v pk2(float a) {
  return __builtin_bit_cast(half2v, __builtin_amdgcn_cvt_pkrtz(a, a));
}

// ---- fmat body (fp64) ----
__device__ void fmat_compute(const float* __restrict__ P1f,
                             const float* __restrict__ P2f,
                             double* __restrict__ Fout, int n) {
  double p1[3][4], p2[3][4];
  for (int i = 0; i < 3; ++i)
    for (int j = 0; j < 4; ++j) {
      p1[i][j] = (double)P1f[n * 12 + i * 4 + j];
      p2[i][j] = (double)P2f[n * 12 + i * 4 + j];
    }
  double A[3][3];
  for (int i = 0; i < 3; ++i)
    for (int j = 0; j < 3; ++j) {
      double s = 0;
      for (int k = 0; k < 4; ++k) s += p1[i][k] * p1[j][k];
      A[i][j] = s;
    }
  double det = A[0][0] * (A[1][1] * A[2][2] - A[1][2] * A[2][1])
             - A[0][1] * (A[1][0] * A[2][2] - A[1][2] * A[2][0])
             + A[0][2] * (A[1][0] * A[2][1] - A[1][1] * A[2][0]);
  double id = 1.0 / det;
  double Ai[3][3];
  Ai[0][0] = (A[1][1] * A[2][2] - A[1][2] * A[2][1]) * id;
  Ai[0][1] = (A[0][2] * A[2][1] - A[0][1] * A[2][2]) * id;
  Ai[0][2] = (A[0][1] * A[1][2] - A[0][2] * A[1][1]) * id;
  Ai[1][0] = (A[1][2] * A[2][0] - A[1][0] * A[2][2]) * id;
  Ai[1][1] = (A[0][0] * A[2][2] - A[0][2] * A[2][0]) * id;
  Ai[1][2] = (A[0][2] * A[1][0] - A[0][0] * A[1][2]) * id;
  Ai[2][0] = (A[1][0] * A[2][1] - A[1][1] * A[2][0]) * id;
  Ai[2][1] = (A[0][1] * A[2][0] - A[0][0] * A[2][1]) * id;
  Ai[2][2] = (A[0][0] * A[1][1] - A[0][1] * A[1][0]) * id;
  double Pi[4][3];
  for (int i = 0; i < 4; ++i)
    for (int j = 0; j < 3; ++j) {
      double s = 0;
      for (int k = 0; k < 3; ++k) s += p1[k][i] * Ai[k][j];
      Pi[i][j] = s;
    }
  double M[3][3];
  for (int i = 0; i < 3; ++i)
    for (int j = 0; j < 3; ++j) {
      double s = 0;
      for (int k = 0; k < 4; ++k) s += p2[i][k] * Pi[k][j];
      M[i][j] = s;
    }
  double nv[4];
  {
    auto det3 = [&](int ca, int cb, int cc) {
      return p1[0][ca] * (p1[1][cb] * p1[2][cc] - p1[1][cc] * p1[2][cb])
           - p1[0][cb] * (p1[1][ca] * p1[2][cc] - p1[1][cc] * p1[2][ca])
           + p1[0][cc] * (p1[1][ca] * p1[2][cb] - p1[1][cb] * p1[2][ca]);
    };
    nv[0] =  det3(1, 2, 3);
    nv[1] = -det3(0, 2, 3);
    nv[2] =  det3(0, 1, 3);
    nv[3] = -det3(0, 1, 2);
  }
  double nn = sqrt(nv[0]*nv[0] + nv[1]*nv[1] + nv[2]*nv[2] + nv[3]*nv[3]);
  for (int i = 0; i < 4; ++i) nv[i] /= nn;
  double e2[3];
  for (int i = 0; i < 3; ++i) {
    double s = 0;
    for (int j = 0; j < 4; ++j) s += p2[i][j] * nv[j];
    e2[i] = s;
  }
  for (int j = 0; j < 3; ++j) {
    Fout[n * 9 + 0 * 3 + j] = -e2[2] * M[1][j] + e2[1] * M[2][j];
    Fout[n * 9 + 1 * 3 + j] =  e2[2] * M[0][j] - e2[0] * M[2][j];
    Fout[n * 9 + 2 * 3 + j] = -e2[1] * M[0][j] + e2[0] * M[1][j];
  }
}

// ---- Kernel 1: feat2 [N,C,H,W] -> f2t fp16 [N,HW,C]; fused fmat ------------
__global__ __launch_bounds__(256) void prep_kernel(
    const float* __restrict__ feat2,
    const float* __restrict__ P1f, const float* __restrict__ P2f,
    _Float16* __restrict__ f2t, double* __restrict__ Fd) {
  __shared__ float tile[32][33];
  const int n  = blockIdx.z;
  const int p0 = blockIdx.x * 32;
  const int c0 = blockIdx.y * 32;
  const int tx = threadIdx.x, ty = threadIdx.y;   // block (32,8)
  const float* src = feat2 + (size_t)n * (C * HW);
#pragma unroll
  for (int j = 0; j < 4; ++j) {
    int cc = c0 + ty + j * 8;
    tile[ty + j * 8][tx] = src[(size_t)cc * HW + p0 + tx];
  }
  __syncthreads();
  {
    const int tid = ty * 32 + tx;
    const int pp = tid >> 3;        // 0..31
    const int cp = tid & 7;         // 0..7
    _Float16* dst = f2t + (size_t)n * (HW * C) + (size_t)(p0 + pp) * C + c0;
#pragma unroll
    for (int jj = 0; jj < 2; ++jj) {
      const int cc = (cp + jj * 8) * 2;          // 0,2,..,30
      half2v h2;
      h2.x = (_Float16)tile[cc][pp];
      h2.y = (_Float16)tile[cc + 1][pp];
      *(half2v*)(dst + cc) = h2;
    }
  }
  if (n == 0 && blockIdx.x == 0 && blockIdx.y == 0) {
    int t = ty * 32 + tx;
    if (t < NB) fmat_compute(P1f, P2f, Fd, t);
  }
}

// ---- 32-lane-group sum: 4 DPP steps (VALU) + 1 ds_swizzle (xor16) ----------
__device__ __forceinline__ float groupsum32(float v) {
  v += __int_as_float(__builtin_amdgcn_update_dpp(
         0, __float_as_int(v), 0xB1, 0xF, 0xF, true));   // quad_perm xor1
  v += __int_as_float(__builtin_amdgcn_update_dpp(
         0, __float_as_int(v), 0x4E, 0xF, 0xF, true));   // quad_perm xor2
  v += __int_as_float(__builtin_amdgcn_update_dpp(
         0, __float_as_int(v), 0x124, 0xF, 0xF, true));  // row_ror:4
  v += __int_as_float(__builtin_amdgcn_update_dpp(
         0, __float_as_int(v), 0x128, 0xF, 0xF, true));  // row_ror:8
  v += __int_as_float(__builtin_amdgcn_ds_swizzle(
         __float_as_int(v), 0x401F));                    // xor16
  return v;
}

// ---- Kernel 2: 2 px/wave, 32 lanes/px, 8 ch/lane, 2-deep prefetch ----------
// Hot math in native packed forms: bilinear+acc on half2v (v_pk_fma_f16),
// dot via fmaf(f32,(float)f16,f32) (v_fma_mix). Acc in fp16 (defer-max T=4
// bounds e<=e^4 so |acc| <= ~1e4 < f16 max). Corners fully clamped in-bounds.
struct Stage {
  uint4 a, b, c, d;              // 4 corners x 8 fp16 channels
  half2v wa, wb, wc, wd;         // broadcast-packed bilinear weights
};

__global__ __launch_bounds__(256) void epi_main(
    const float* __restrict__ feat1, const _Float16* __restrict__ f2t,
    const double* __restrict__ Fd, float* __restrict__ out) {
  const int tid  = threadIdx.x;
  const int lane = tid & 63;
  const int wv   = tid >> 6;
  const int grp  = lane >> 5;               // pixel within wave (0/1)
  const int cl   = lane & 31;               // channel lane
  const int bid  = blockIdx.x;
  const int r    = bid & 7;
  const int k    = bid >> 3;                // 0..127
  const int n    = r >> 2;
  const int sub  = r & 3;                   // row stripe
  const int p    = (sub * 128 + k) * 8 + wv * 2 + grp;
  const int h = p >> 6, w = p & (W - 1);
  const int cb = cl * 8;                    // channel base for this lane

  // --- f1: 8 channels cb..cb+7 straight from [N,C,H,W] (read once, f32) ---
  float f1r[8];
  {
    const float* f1b = feat1 + ((size_t)n * C + cb) * HW + p;
#pragma unroll
    for (int i = 0; i < 8; ++i) f1r[i] = f1b[(size_t)i * HW];
  }

  // --- epipolar line + endpoint pick, fp32 ---
  const double* Fdp = Fd + n * 9;
  const float F0 = (float)Fdp[0], F1 = (float)Fdp[1], F2 = (float)Fdp[2];
  const float F3 = (float)Fdp[3], F4 = (float)Fdp[4], F5 = (float)Fdp[5];
  const float F6 = (float)Fdp[6], F7 = (float)Fdp[7], F8 = (float)Fdp[8];
  const float X = w * 4.0f + 1.5f;
  const float Y = h * 4.0f + 1.5f;
  const float a = F0 * X + F1 * Y + F2;
  const float b = F3 * X + F4 * Y + F5;
  const float c = F6 * X + F7 * Y + F8;
  const float a_s = (fabsf(a) < 1e-3f) ? 1e-3f : a;
  const float b_s = (fabsf(b) < 1e-3f) ? 1e-3f : b;
  const float xmin = 1.5f, xmax = 253.5f, ymin = 1.5f, ymax = 253.5f, tol = 0.01f;
  float cx[4], cy[4];
  cx[0] = xmin;  cy[0] = -(c + a * xmin) / b_s;
  cx[1] = xmax;  cy[1] = -(c + a * xmax) / b_s;
  cx[2] = -(c + b * ymin) / a_s;  cy[2] = ymin;
  cx[3] = -(c + b * ymax) / a_s;  cy[3] = ymax;
  bool valid[4];
#pragma unroll
  for (int i = 0; i < 4; ++i)
    valid[i] = (cx[i] >= xmin - tol) && (cx[i] <= xmax + tol) &&
               (cy[i] >= ymin - tol) && (cy[i] <= ymax + tol);
#pragma unroll
  for (int i = 0; i < 4; ++i)
    if (!valid[i]) { cx[i] = xmin - 10000.0f; cy[i] = ymin - 10000.0f; }
  int pk0 = -1, pk1 = -1;
#pragma unroll
  for (int i = 0; i < 4; ++i)
    if (valid[i]) { if (pk0 < 0) pk0 = i; else if (pk1 < 0) pk1 = i; }
#pragma unroll
  for (int i = 0; i < 4; ++i)
    if (!valid[i]) { if (pk0 < 0) pk0 = i; else if (pk1 < 0) pk1 = i; }
  // endpoints in destination-pixel coords: x=(px-1.5)*0.25
  const float x0p = (cx[pk0] - 1.5f) * 0.25f;
  const float y0p = (cy[pk0] - 1.5f) * 0.25f;
  const float pdx = (cx[pk1] - 1.5f) * 0.25f - x0p;
  const float pdy = (cy[pk1] - 1.5f) * 0.25f - y0p;

  const _Float16* f2b = f2t + (size_t)n * HW * C + cb;

  float m = -1e30f, l = 0.f;
  half2v acc2[4];
#pragma unroll
  for (int i = 0; i < 4; ++i) acc2[i] = (half2v)(_Float16)0;

  // issue sample s's loads + packed weights into st (no use of results here)
  auto issue = [&](int s, Stage& st) {
    const float t = (float)s * (1.0f / 31.0f);
    const float x = fmaf(t, pdx, x0p);
    const float y = fmaf(t, pdy, y0p);
    const float xf = floorf(x), yf = floorf(y);
    const float wx = x - xf, wy = y - yf;
    const int x0 = (int)xf, y0 = (int)yf;
    const bool bx0 = ((unsigned)x0 < W), bx1 = ((unsigned)(x0 + 1) < W);
    const bool by0 = ((unsigned)y0 < H), by1 = ((unsigned)(y0 + 1) < H);
    const int xc0 = min(max(x0, 0), W - 1);
    const int xc1 = min(max(x0 + 1, 0), W - 1);
    const int yc0 = min(max(y0, 0), H - 1);
    const int yc1 = min(max(y0 + 1, 0), H - 1);
    const float u0 = 1.f - wx, v0 = 1.f - wy;
    const float w00 = v0 * u0 * (float)(bx0 & by0);
    const float w01 = v0 * wx * (float)(bx1 & by0);
    const float w10 = wy * u0 * (float)(bx0 & by1);
    const float w11 = wy * wx * (float)(bx1 & by1);
    st.wa = pk2(w00);
    st.wb = pk2(w01);
    st.wc = pk2(w10);
    st.wd = pk2(w11);
    const int r0 = yc0 * W, r1 = yc1 * W;
    st.a = *(const uint4*)(f2b + (r0 + xc0) * C);
    st.b = *(const uint4*)(f2b + (r0 + xc1) * C);
    st.c = *(const uint4*)(f2b + (r1 + xc0) * C);
    st.d = *(const uint4*)(f2b + (r1 + xc1) * C);
  };

  auto process = [&](const Stage& st) {
    // bilinear in packed fp16 (v_pk_fma_f16), 4x half2 = 8 channels
    half2v q[4];
    {
      const uint* ap = (const uint*)&st.a;
      const uint* bp = (const uint*)&st.b;
      const uint* cp = (const uint*)&st.c;
      const uint* dp = (const uint*)&st.d;
#pragma unroll
      for (int j = 0; j < 4; ++j) {
        half2v qa = __builtin_bit_cast(half2v, ap[j]) * st.wa;
        qa += __builtin_bit_cast(half2v, bp[j]) * st.wb;
        qa += __builtin_bit_cast(half2v, cp[j]) * st.wc;
        qa += __builtin_bit_cast(half2v, dp[j]) * st.wd;
        q[j] = qa;
      }
    }
    // dot: canonical mix pattern f32 += f32 * (float)f16
    float part = 0.f;
#pragma unroll
    for (int j = 0; j < 4; ++j) {
      part = fmaf(f1r[2 * j],     (float)q[j].x, part);
      part = fmaf(f1r[2 * j + 1], (float)q[j].y, part);
    }
    part = groupsum32(part);

    if (__any(part > m + 4.f)) {          // defer-max (T=4: e<=e^4, f16-safe)
      const float mn = fmaxf(m, part);
      const float sc = __expf(m - mn);
      l *= sc;
      const half2v sch = pk2(sc);
#pragma unroll
      for (int i = 0; i < 4; ++i) acc2[i] *= sch;
      m = mn;
    }
    const float e = __expf(part - m);
    l += e;
    const half2v eh = pk2(e);
#pragma unroll
    for (int i = 0; i < 4; ++i) acc2[i] += eh * q[i];   // v_pk_fma_f16
  };

  // 2-deep software pipeline over all 32 samples; stage slots static
  Stage sA, sB, sC;
  issue(0, sA);
  issue(1, sB);
  for (int k3 = 0; k3 < 30; k3 += 3) {
    issue(k3 + 2, sC);
    process(sA);
    issue(k3 + 3, sA);
    process(sB);
    issue(k3 + 4, sB);
    process(sC);
  }
  process(sA);   // s = 30
  process(sB);   // s = 31

  const float inv = 1.0f / l;
  float* ob = out + (size_t)n * C * HW + (size_t)cb * HW + p;
#pragma unroll
  for (int i = 0; i < 4; ++i) {
    ob[(size_t)(2 * i) * HW]     = (float)acc2[i].x * inv;
    ob[(size_t)(2 * i + 1) * HW] = (float)acc2[i].y * inv;
  }
}

extern "C" void kernel_launch(void* const* d_in, const int* in_sizes, int n_in,
                              void* d_out, int out_size, void* d_ws, size_t ws_size,
                              hipStream_t stream) {
  const float* feat1 = (const float*)d_in[0];
  const float* feat2 = (const float*)d_in[1];
  const float* P1 = (const float*)d_in[2];
  const float* P2 = (const float*)d_in[3];
  float* out = (float*)d_out;

  char* ws = (char*)d_ws;
  _Float16* f2t = (_Float16*)ws;                            // 4 MB @ 0
  double*   Fd  = (double*)(ws + (5u << 20));               // @ 5 MB

  prep_kernel<<<dim3(HW / 32, C / 32, NB), dim3(32, 8), 0, stream>>>(
      feat2, P1, P2, f2t, Fd);
  epi_main<<<NB * HW / 8, 256, 0, stream>>>(feat1, f2t, Fd, out);
}

// Round 15
// 39.512 us; speedup vs baseline: 1.1277x; 1.0294x over previous
//
#include <hip/hip_runtime.h>
#include <math.h>

#define H 64
#define W 64
#define C 256
#define NB 2
#define SS 32
#define HW (H*W)

typedef __attribute__((ext_vector_type(2))) _Float16 half2v;
typedef __attribute__((ext_vector_type(2))) __fp16   fp16x2;

// cvt_pkrtz returns an __fp16 vector; bit-cast to our half2v (same layout)
__device__ __forceinline__ half2v pk2(float a) {
  return __builtin_bit_cast(half2v, __builtin_amdgcn_cvt_pkrtz(a, a));
}

// f32 += dot2(f16x2, f16x2) -- v_dot2_f32_f16 when available
__device__ __forceinline__ float fdot2(half2v a, half2v b, float c) {
#if __has_builtin(__builtin_amdgcn_fdot2)
  return __builtin_amdgcn_fdot2(__builtin_bit_cast(fp16x2, a),
                                __builtin_bit_cast(fp16x2, b), c, false);
#else
  c = fmaf((float)a.x, (float)b.x, c);
  c = fmaf((float)a.y, (float)b.y, c);
  return c;
#endif
}

// ---- fmat body (fp64) ----
__device__ void fmat_compute(const float* __restrict__ P1f,
                             const float* __restrict__ P2f,
                             double* __restrict__ Fout, int n) {
  double p1[3][4], p2[3][4];
  for (int i = 0; i < 3; ++i)
    for (int j = 0; j < 4; ++j) {
      p1[i][j] = (double)P1f[n * 12 + i * 4 + j];
      p2[i][j] = (double)P2f[n * 12 + i * 4 + j];
    }
  double A[3][3];
  for (int i = 0; i < 3; ++i)
    for (int j = 0; j < 3; ++j) {
      double s = 0;
      for (int k = 0; k < 4; ++k) s += p1[i][k] * p1[j][k];
      A[i][j] = s;
    }
  double det = A[0][0] * (A[1][1] * A[2][2] - A[1][2] * A[2][1])
             - A[0][1] * (A[1][0] * A[2][2] - A[1][2] * A[2][0])
             + A[0][2] * (A[1][0] * A[2][1] - A[1][1] * A[2][0]);
  double id = 1.0 / det;
  double Ai[3][3];
  Ai[0][0] = (A[1][1] * A[2][2] - A[1][2] * A[2][1]) * id;
  Ai[0][1] = (A[0][2] * A[2][1] - A[0][1] * A[2][2]) * id;
  Ai[0][2] = (A[0][1] * A[1][2] - A[0][2] * A[1][1]) * id;
  Ai[1][0] = (A[1][2] * A[2][0] - A[1][0] * A[2][2]) * id;
  Ai[1][1] = (A[0][0] * A[2][2] - A[0][2] * A[2][0]) * id;
  Ai[1][2] = (A[0][2] * A[1][0] - A[0][0] * A[1][2]) * id;
  Ai[2][0] = (A[1][0] * A[2][1] - A[1][1] * A[2][0]) * id;
  Ai[2][1] = (A[0][1] * A[2][0] - A[0][0] * A[2][1]) * id;
  Ai[2][2] = (A[0][0] * A[1][1] - A[0][1] * A[1][0]) * id;
  double Pi[4][3];
  for (int i = 0; i < 4; ++i)
    for (int j = 0; j < 3; ++j) {
      double s = 0;
      for (int k = 0; k < 3; ++k) s += p1[k][i] * Ai[k][j];
      Pi[i][j] = s;
    }
  double M[3][3];
  for (int i = 0; i < 3; ++i)
    for (int j = 0; j < 3; ++j) {
      double s = 0;
      for (int k = 0; k < 4; ++k) s += p2[i][k] * Pi[k][j];
      M[i][j] = s;
    }
  double nv[4];
  {
    auto det3 = [&](int ca, int cb, int cc) {
      return p1[0][ca] * (p1[1][cb] * p1[2][cc] - p1[1][cc] * p1[2][cb])
           - p1[0][cb] * (p1[1][ca] * p1[2][cc] - p1[1][cc] * p1[2][ca])
           + p1[0][cc] * (p1[1][ca] * p1[2][cb] - p1[1][cb] * p1[2][ca]);
    };
    nv[0] =  det3(1, 2, 3);
    nv[1] = -det3(0, 2, 3);
    nv[2] =  det3(0, 1, 3);
    nv[3] = -det3(0, 1, 2);
  }
  double nn = sqrt(nv[0]*nv[0] + nv[1]*nv[1] + nv[2]*nv[2] + nv[3]*nv[3]);
  for (int i = 0; i < 4; ++i) nv[i] /= nn;
  double e2[3];
  for (int i = 0; i < 3; ++i) {
    double s = 0;
    for (int j = 0; j < 4; ++j) s += p2[i][j] * nv[j];
    e2[i] = s;
  }
  for (int j = 0; j < 3; ++j) {
    Fout[n * 9 + 0 * 3 + j] = -e2[2] * M[1][j] + e2[1] * M[2][j];
    Fout[n * 9 + 1 * 3 + j] =  e2[2] * M[0][j] - e2[0] * M[2][j];
    Fout[n * 9 + 2 * 3 + j] = -e2[1] * M[0][j] + e2[0] * M[1][j];
  }
}

// ---- Kernel 1: feat2 [N,C,H,W] -> f2t fp16 [N,HW,C]; fused fmat ------------
__global__ __launch_bounds__(256) void prep_kernel(
    const float* __restrict__ feat2,
    const float* __restrict__ P1f, const float* __restrict__ P2f,
    _Float16* __restrict__ f2t, double* __restrict__ Fd) {
  __shared__ float tile[32][33];
  const int n  = blockIdx.z;
  const int p0 = blockIdx.x * 32;
  const int c0 = blockIdx.y * 32;
  const int tx = threadIdx.x, ty = threadIdx.y;   // block (32,8)
  const float* src = feat2 + (size_t)n * (C * HW);
#pragma unroll
  for (int j = 0; j < 4; ++j) {
    int cc = c0 + ty + j * 8;
    tile[ty + j * 8][tx] = src[(size_t)cc * HW + p0 + tx];
  }
  __syncthreads();
  {
    const int tid = ty * 32 + tx;
    const int pp = tid >> 3;        // 0..31
    const int cp = tid & 7;         // 0..7
    _Float16* dst = f2t + (size_t)n * (HW * C) + (size_t)(p0 + pp) * C + c0;
#pragma unroll
    for (int jj = 0; jj < 2; ++jj) {
      const int cc = (cp + jj * 8) * 2;          // 0,2,..,30
      half2v h2;
      h2.x = (_Float16)tile[cc][pp];
      h2.y = (_Float16)tile[cc + 1][pp];
      *(half2v*)(dst + cc) = h2;
    }
  }
  if (n == 0 && blockIdx.x == 0 && blockIdx.y == 0) {
    int t = ty * 32 + tx;
    if (t < NB) fmat_compute(P1f, P2f, Fd, t);
  }
}

// ---- 32-lane-group sum: 4 DPP steps (VALU) + 1 ds_swizzle (xor16) ----------
__device__ __forceinline__ float groupsum32(float v) {
  v += __int_as_float(__builtin_amdgcn_update_dpp(
         0, __float_as_int(v), 0xB1, 0xF, 0xF, true));   // quad_perm xor1
  v += __int_as_float(__builtin_amdgcn_update_dpp(
         0, __float_as_int(v), 0x4E, 0xF, 0xF, true));   // quad_perm xor2
  v += __int_as_float(__builtin_amdgcn_update_dpp(
         0, __float_as_int(v), 0x124, 0xF, 0xF, true));  // row_ror:4
  v += __int_as_float(__builtin_amdgcn_update_dpp(
         0, __float_as_int(v), 0x128, 0xF, 0xF, true));  // row_ror:8
  v += __int_as_float(__builtin_amdgcn_ds_swizzle(
         __float_as_int(v), 0x401F));                    // xor16
  return v;
}

// ---- Kernel 2: 2 px/wave, 32 lanes/px, 8 ch/lane; pairwise plain loop ------
// No manual stage rotation: two independent samples per iteration give the
// compiler natural ILP to schedule loads early without persistent Stage regs.
// Hot math packed f16 (v_pk_fma_f16); dot via v_dot2_f32_f16; fp16 acc with
// defer-max T=4 (e<=e^4, |acc| <= ~1.8e3 < f16 max). Corners fully clamped.
__global__ __launch_bounds__(256) void epi_main(
    const float* __restrict__ feat1, const _Float16* __restrict__ f2t,
    const double* __restrict__ Fd, float* __restrict__ out) {
  const int tid  = threadIdx.x;
  const int lane = tid & 63;
  const int wv   = tid >> 6;
  const int grp  = lane >> 5;               // pixel within wave (0/1)
  const int cl   = lane & 31;               // channel lane
  const int bid  = blockIdx.x;
  const int r    = bid & 7;
  const int k    = bid >> 3;                // 0..127
  const int n    = r >> 2;
  const int sub  = r & 3;                   // row stripe
  const int p    = (sub * 128 + k) * 8 + wv * 2 + grp;
  const int h = p >> 6, w = p & (W - 1);
  const int cb = cl * 8;                    // channel base for this lane

  // --- f1: 8 channels cb..cb+7, packed to 4x half2 for v_dot2 ---
  half2v f1h[4];
  {
    const float* f1b = feat1 + ((size_t)n * C + cb) * HW + p;
#pragma unroll
    for (int i = 0; i < 4; ++i) {
      const float lo = f1b[(size_t)(2 * i) * HW];
      const float hi = f1b[(size_t)(2 * i + 1) * HW];
      f1h[i] = __builtin_bit_cast(half2v, __builtin_amdgcn_cvt_pkrtz(lo, hi));
    }
  }

  // --- epipolar line + endpoint pick, fp32 ---
  const double* Fdp = Fd + n * 9;
  const float F0 = (float)Fdp[0], F1 = (float)Fdp[1], F2 = (float)Fdp[2];
  const float F3 = (float)Fdp[3], F4 = (float)Fdp[4], F5 = (float)Fdp[5];
  const float F6 = (float)Fdp[6], F7 = (float)Fdp[7], F8 = (float)Fdp[8];
  const float X = w * 4.0f + 1.5f;
  const float Y = h * 4.0f + 1.5f;
  const float a = F0 * X + F1 * Y + F2;
  const float b = F3 * X + F4 * Y + F5;
  const float c = F6 * X + F7 * Y + F8;
  const float a_s = (fabsf(a) < 1e-3f) ? 1e-3f : a;
  const float b_s = (fabsf(b) < 1e-3f) ? 1e-3f : b;
  const float xmin = 1.5f, xmax = 253.5f, ymin = 1.5f, ymax = 253.5f, tol = 0.01f;
  float cx[4], cy[4];
  cx[0] = xmin;  cy[0] = -(c + a * xmin) / b_s;
  cx[1] = xmax;  cy[1] = -(c + a * xmax) / b_s;
  cx[2] = -(c + b * ymin) / a_s;  cy[2] = ymin;
  cx[3] = -(c + b * ymax) / a_s;  cy[3] = ymax;
  bool valid[4];
#pragma unroll
  for (int i = 0; i < 4; ++i)
    valid[i] = (cx[i] >= xmin - tol) && (cx[i] <= xmax + tol) &&
               (cy[i] >= ymin - tol) && (cy[i] <= ymax + tol);
#pragma unroll
  for (int i = 0; i < 4; ++i)
    if (!valid[i]) { cx[i] = xmin - 10000.0f; cy[i] = ymin - 10000.0f; }
  int pk0 = -1, pk1 = -1;
#pragma unroll
  for (int i = 0; i < 4; ++i)
    if (valid[i]) { if (pk0 < 0) pk0 = i; else if (pk1 < 0) pk1 = i; }
#pragma unroll
  for (int i = 0; i < 4; ++i)
    if (!valid[i]) { if (pk0 < 0) pk0 = i; else if (pk1 < 0) pk1 = i; }
  // endpoints in destination-pixel coords: x=(px-1.5)*0.25
  const float x0p = (cx[pk0] - 1.5f) * 0.25f;
  const float y0p = (cy[pk0] - 1.5f) * 0.25f;
  const float pdx = (cx[pk1] - 1.5f) * 0.25f - x0p;
  const float pdy = (cy[pk1] - 1.5f) * 0.25f - y0p;

  const _Float16* f2b = f2t + (size_t)n * HW * C + cb;

  float m = -1e30f, l = 0.f;
  half2v acc2[4];
#pragma unroll
  for (int i = 0; i < 4; ++i) acc2[i] = (half2v)(_Float16)0;

  // sample s: loads + packed weights (independent per s; compiler schedules)
  auto fetch = [&](int s, uint4& A, uint4& B, uint4& Cc, uint4& D,
                   half2v& wa, half2v& wb, half2v& wc, half2v& wd) {
    const float t = (float)s * (1.0f / 31.0f);
    const float x = fmaf(t, pdx, x0p);
    const float y = fmaf(t, pdy, y0p);
    const float xf = floorf(x), yf = floorf(y);
    const float wx = x - xf, wy = y - yf;
    const int x0 = (int)xf, y0 = (int)yf;
    const bool bx0 = ((unsigned)x0 < W), bx1 = ((unsigned)(x0 + 1) < W);
    const bool by0 = ((unsigned)y0 < H), by1 = ((unsigned)(y0 + 1) < H);
    const int xc0 = min(max(x0, 0), W - 1);
    const int xc1 = min(max(x0 + 1, 0), W - 1);
    const int yc0 = min(max(y0, 0), H - 1);
    const int yc1 = min(max(y0 + 1, 0), H - 1);
    const float u0 = 1.f - wx, v0 = 1.f - wy;
    wa = pk2(v0 * u0 * (float)(bx0 & by0));
    wb = pk2(v0 * wx * (float)(bx1 & by0));
    wc = pk2(wy * u0 * (float)(bx0 & by1));
    wd = pk2(wy * wx * (float)(bx1 & by1));
    const int r0 = yc0 * W, r1 = yc1 * W;
    A  = *(const uint4*)(f2b + (r0 + xc0) * C);
    B  = *(const uint4*)(f2b + (r0 + xc1) * C);
    Cc = *(const uint4*)(f2b + (r1 + xc0) * C);
    D  = *(const uint4*)(f2b + (r1 + xc1) * C);
  };

  auto bilin = [&](const uint4& A, const uint4& B, const uint4& Cc,
                   const uint4& D, half2v wa, half2v wb, half2v wc, half2v wd,
                   half2v q[4], float& part) {
    const uint* ap = (const uint*)&A;
    const uint* bp = (const uint*)&B;
    const uint* cp = (const uint*)&Cc;
    const uint* dp = (const uint*)&D;
    part = 0.f;
#pragma unroll
    for (int j = 0; j < 4; ++j) {
      half2v qa = __builtin_bit_cast(half2v, ap[j]) * wa;
      qa += __builtin_bit_cast(half2v, bp[j]) * wb;
      qa += __builtin_bit_cast(half2v, cp[j]) * wc;
      qa += __builtin_bit_cast(half2v, dp[j]) * wd;
      q[j] = qa;
      part = fdot2(qa, f1h[j], part);
    }
  };

  // pairwise plain loop: 2 independent samples per iteration, joint softmax
#pragma unroll
  for (int s = 0; s < SS; s += 2) {
    uint4 A0, B0, C0, D0, A1, B1, C1, D1;
    half2v wa0, wb0, wc0, wd0, wa1, wb1, wc1, wd1;
    fetch(s,     A0, B0, C0, D0, wa0, wb0, wc0, wd0);
    fetch(s + 1, A1, B1, C1, D1, wa1, wb1, wc1, wd1);

    half2v q0[4], q1[4];
    float p0, p1;
    bilin(A0, B0, C0, D0, wa0, wb0, wc0, wd0, q0, p0);
    bilin(A1, B1, C1, D1, wa1, wb1, wc1, wd1, q1, p1);
    p0 = groupsum32(p0);
    p1 = groupsum32(p1);

    const float mx = fmaxf(p0, p1);
    if (__any(mx > m + 4.f)) {            // defer-max (T=4), joint for pair
      const float mn = fmaxf(m, mx);
      const float sc = __expf(m - mn);
      l *= sc;
      const half2v sch = pk2(sc);
#pragma unroll
      for (int i = 0; i < 4; ++i) acc2[i] *= sch;
      m = mn;
    }
    const float e0 = __expf(p0 - m);
    const float e1 = __expf(p1 - m);
    l += e0 + e1;
    const half2v eh0 = pk2(e0);
    const half2v eh1 = pk2(e1);
#pragma unroll
    for (int i = 0; i < 4; ++i) {
      acc2[i] += eh0 * q0[i];             // v_pk_fma_f16
      acc2[i] += eh1 * q1[i];
    }
  }

  const float inv = 1.0f / l;
  float* ob = out + (size_t)n * C * HW + (size_t)cb * HW + p;
#pragma unroll
  for (int i = 0; i < 4; ++i) {
    ob[(size_t)(2 * i) * HW]     = (float)acc2[i].x * inv;
    ob[(size_t)(2 * i + 1) * HW] = (float)acc2[i].y * inv;
  }
}

extern "C" void kernel_launch(void* const* d_in, const int* in_sizes, int n_in,
                              void* d_out, int out_size, void* d_ws, size_t ws_size,
                              hipStream_t stream) {
  const float* feat1 = (const float*)d_in[0];
  const float* feat2 = (const float*)d_in[1];
  const float* P1 = (const float*)d_in[2];
  const float* P2 = (const float*)d_in[3];
  float* out = (float*)d_out;

  char* ws = (char*)d_ws;
  _Float16* f2t = (_Float16*)ws;                            // 4 MB @ 0
  double*   Fd  = (double*)(ws + (5u << 20));               // @ 5 MB

  prep_kernel<<<dim3(HW / 32, C / 32, NB), dim3(32, 8), 0, stream>>>(
      feat2, P1, P2, f2t, Fd);
  epi_main<<<NB * HW / 8, 256, 0, stream>>>(feat1, f2t, Fd, out);
}

// Round 16
// 39.263 us; speedup vs baseline: 1.1348x; 1.0064x over previous
//
#include <hip/hip_runtime.h>
#include <math.h>

#define H 64
#define W 64
#define C 256
#define NB 2
#define SS 32
#define HW (H*W)

typedef __attribute__((ext_vector_type(2))) _Float16 half2v;
typedef __attribute__((ext_vector_type(2))) __fp16   fp16x2;

// cvt_pkrtz returns an __fp16 vector; bit-cast to our half2v (same layout)
__device__ __forceinline__ half2v pk2(float a) {
  return __builtin_bit_cast(half2v, __builtin_amdgcn_cvt_pkrtz(a, a));
}

// f32 += dot2(f16x2, f16x2) -- v_dot2_f32_f16 when available
__device__ __forceinline__ float fdot2(half2v a, half2v b, float c) {
#if __has_builtin(__builtin_amdgcn_fdot2)
  return __builtin_amdgcn_fdot2(__builtin_bit_cast(fp16x2, a),
                                __builtin_bit_cast(fp16x2, b), c, false);
#else
  c = fmaf((float)a.x, (float)b.x, c);
  c = fmaf((float)a.y, (float)b.y, c);
  return c;
#endif
}

// ---- fmat body (fp64) ----
__device__ void fmat_compute(const float* __restrict__ P1f,
                             const float* __restrict__ P2f,
                             double* __restrict__ Fout, int n) {
  double p1[3][4], p2[3][4];
  for (int i = 0; i < 3; ++i)
    for (int j = 0; j < 4; ++j) {
      p1[i][j] = (double)P1f[n * 12 + i * 4 + j];
      p2[i][j] = (double)P2f[n * 12 + i * 4 + j];
    }
  double A[3][3];
  for (int i = 0; i < 3; ++i)
    for (int j = 0; j < 3; ++j) {
      double s = 0;
      for (int k = 0; k < 4; ++k) s += p1[i][k] * p1[j][k];
      A[i][j] = s;
    }
  double det = A[0][0] * (A[1][1] * A[2][2] - A[1][2] * A[2][1])
             - A[0][1] * (A[1][0] * A[2][2] - A[1][2] * A[2][0])
             + A[0][2] * (A[1][0] * A[2][1] - A[1][1] * A[2][0]);
  double id = 1.0 / det;
  double Ai[3][3];
  Ai[0][0] = (A[1][1] * A[2][2] - A[1][2] * A[2][1]) * id;
  Ai[0][1] = (A[0][2] * A[2][1] - A[0][1] * A[2][2]) * id;
  Ai[0][2] = (A[0][1] * A[1][2] - A[0][2] * A[1][1]) * id;
  Ai[1][0] = (A[1][2] * A[2][0] - A[1][0] * A[2][2]) * id;
  Ai[1][1] = (A[0][0] * A[2][2] - A[0][2] * A[2][0]) * id;
  Ai[1][2] = (A[0][2] * A[1][0] - A[0][0] * A[1][2]) * id;
  Ai[2][0] = (A[1][0] * A[2][1] - A[1][1] * A[2][0]) * id;
  Ai[2][1] = (A[0][1] * A[2][0] - A[0][0] * A[2][1]) * id;
  Ai[2][2] = (A[0][0] * A[1][1] - A[0][1] * A[1][0]) * id;
  double Pi[4][3];
  for (int i = 0; i < 4; ++i)
    for (int j = 0; j < 3; ++j) {
      double s = 0;
      for (int k = 0; k < 3; ++k) s += p1[k][i] * Ai[k][j];
      Pi[i][j] = s;
    }
  double M[3][3];
  for (int i = 0; i < 3; ++i)
    for (int j = 0; j < 3; ++j) {
      double s = 0;
      for (int k = 0; k < 4; ++k) s += p2[i][k] * Pi[k][j];
      M[i][j] = s;
    }
  double nv[4];
  {
    auto det3 = [&](int ca, int cb, int cc) {
      return p1[0][ca] * (p1[1][cb] * p1[2][cc] - p1[1][cc] * p1[2][cb])
           - p1[0][cb] * (p1[1][ca] * p1[2][cc] - p1[1][cc] * p1[2][ca])
           + p1[0][cc] * (p1[1][ca] * p1[2][cb] - p1[1][cb] * p1[2][ca]);
    };
    nv[0] =  det3(1, 2, 3);
    nv[1] = -det3(0, 2, 3);
    nv[2] =  det3(0, 1, 3);
    nv[3] = -det3(0, 1, 2);
  }
  double nn = sqrt(nv[0]*nv[0] + nv[1]*nv[1] + nv[2]*nv[2] + nv[3]*nv[3]);
  for (int i = 0; i < 4; ++i) nv[i] /= nn;
  double e2[3];
  for (int i = 0; i < 3; ++i) {
    double s = 0;
    for (int j = 0; j < 4; ++j) s += p2[i][j] * nv[j];
    e2[i] = s;
  }
  for (int j = 0; j < 3; ++j) {
    Fout[n * 9 + 0 * 3 + j] = -e2[2] * M[1][j] + e2[1] * M[2][j];
    Fout[n * 9 + 1 * 3 + j] =  e2[2] * M[0][j] - e2[0] * M[2][j];
    Fout[n * 9 + 2 * 3 + j] = -e2[1] * M[0][j] + e2[0] * M[1][j];
  }
}

// ---- Kernel 1: feat2 [N,C,H,W] -> f2t fp16 [N,HW,C]; fused fmat ------------
__global__ __launch_bounds__(256) void prep_kernel(
    const float* __restrict__ feat2,
    const float* __restrict__ P1f, const float* __restrict__ P2f,
    _Float16* __restrict__ f2t, double* __restrict__ Fd) {
  __shared__ float tile[32][33];
  const int n  = blockIdx.z;
  const int p0 = blockIdx.x * 32;
  const int c0 = blockIdx.y * 32;
  const int tx = threadIdx.x, ty = threadIdx.y;   // block (32,8)
  const float* src = feat2 + (size_t)n * (C * HW);
#pragma unroll
  for (int j = 0; j < 4; ++j) {
    int cc = c0 + ty + j * 8;
    tile[ty + j * 8][tx] = src[(size_t)cc * HW + p0 + tx];
  }
  __syncthreads();
  {
    const int tid = ty * 32 + tx;
    const int pp = tid >> 3;        // 0..31
    const int cp = tid & 7;         // 0..7
    _Float16* dst = f2t + (size_t)n * (HW * C) + (size_t)(p0 + pp) * C + c0;
#pragma unroll
    for (int jj = 0; jj < 2; ++jj) {
      const int cc = (cp + jj * 8) * 2;          // 0,2,..,30
      half2v h2;
      h2.x = (_Float16)tile[cc][pp];
      h2.y = (_Float16)tile[cc + 1][pp];
      *(half2v*)(dst + cc) = h2;
    }
  }
  if (n == 0 && blockIdx.x == 0 && blockIdx.y == 0) {
    int t = ty * 32 + tx;
    if (t < NB) fmat_compute(P1f, P2f, Fd, t);
  }
}

// ---- 32-lane-group sum, pure VALU: 4 DPP + permlane16_swap (xor16) ---------
__device__ __forceinline__ float groupsum32(float v) {
  v += __int_as_float(__builtin_amdgcn_update_dpp(
         0, __float_as_int(v), 0xB1, 0xF, 0xF, true));   // quad_perm xor1
  v += __int_as_float(__builtin_amdgcn_update_dpp(
         0, __float_as_int(v), 0x4E, 0xF, 0xF, true));   // quad_perm xor2
  v += __int_as_float(__builtin_amdgcn_update_dpp(
         0, __float_as_int(v), 0x124, 0xF, 0xF, true));  // row_ror:4
  v += __int_as_float(__builtin_amdgcn_update_dpp(
         0, __float_as_int(v), 0x128, 0xF, 0xF, true));  // row_ror:8
#if __has_builtin(__builtin_amdgcn_permlane16_swap)
  {
    // swap(v,v): r0 = v with each odd 16-row <- even row; r1 = converse.
    // lane i: r0[i]+r1[i] == v[i] + v[i^16]  (within each 32-lane half)
    auto pr = __builtin_amdgcn_permlane16_swap(
        __float_as_int(v), __float_as_int(v), false, false);
    v = __int_as_float(pr[0]) + __int_as_float(pr[1]);
  }
#else
  v += __int_as_float(__builtin_amdgcn_ds_swizzle(
         __float_as_int(v), 0x401F));                    // xor16 (LDS pipe)
#endif
  return v;
}

// ---- Kernel 2: 2 px/wave, 32 lanes/px, 8 ch/lane; pairwise plain loop ------
// Packed-f16 hot math, v_dot2 dot, pure-VALU reduce (no LDS round-trip on the
// per-sample critical chain), fp16 acc with defer-max T=4. Corners clamped.
__global__ __launch_bounds__(256) void epi_main(
    const float* __restrict__ feat1, const _Float16* __restrict__ f2t,
    const double* __restrict__ Fd, float* __restrict__ out) {
  const int tid  = threadIdx.x;
  const int lane = tid & 63;
  const int wv   = tid >> 6;
  const int grp  = lane >> 5;               // pixel within wave (0/1)
  const int cl   = lane & 31;               // channel lane
  const int bid  = blockIdx.x;
  const int r    = bid & 7;
  const int k    = bid >> 3;                // 0..127
  const int n    = r >> 2;
  const int sub  = r & 3;                   // row stripe
  const int p    = (sub * 128 + k) * 8 + wv * 2 + grp;
  const int h = p >> 6, w = p & (W - 1);
  const int cb = cl * 8;                    // channel base for this lane

  // --- f1: 8 channels cb..cb+7, packed to 4x half2 for v_dot2 ---
  half2v f1h[4];
  {
    const float* f1b = feat1 + ((size_t)n * C + cb) * HW + p;
#pragma unroll
    for (int i = 0; i < 4; ++i) {
      const float lo = f1b[(size_t)(2 * i) * HW];
      const float hi = f1b[(size_t)(2 * i + 1) * HW];
      f1h[i] = __builtin_bit_cast(half2v, __builtin_amdgcn_cvt_pkrtz(lo, hi));
    }
  }

  // --- epipolar line + endpoint pick, fp32 ---
  const double* Fdp = Fd + n * 9;
  const float F0 = (float)Fdp[0], F1 = (float)Fdp[1], F2 = (float)Fdp[2];
  const float F3 = (float)Fdp[3], F4 = (float)Fdp[4], F5 = (float)Fdp[5];
  const float F6 = (float)Fdp[6], F7 = (float)Fdp[7], F8 = (float)Fdp[8];
  const float X = w * 4.0f + 1.5f;
  const float Y = h * 4.0f + 1.5f;
  const float a = F0 * X + F1 * Y + F2;
  const float b = F3 * X + F4 * Y + F5;
  const float c = F6 * X + F7 * Y + F8;
  const float a_s = (fabsf(a) < 1e-3f) ? 1e-3f : a;
  const float b_s = (fabsf(b) < 1e-3f) ? 1e-3f : b;
  const float xmin = 1.5f, xmax = 253.5f, ymin = 1.5f, ymax = 253.5f, tol = 0.01f;
  float cx[4], cy[4];
  cx[0] = xmin;  cy[0] = -(c + a * xmin) / b_s;
  cx[1] = xmax;  cy[1] = -(c + a * xmax) / b_s;
  cx[2] = -(c + b * ymin) / a_s;  cy[2] = ymin;
  cx[3] = -(c + b * ymax) / a_s;  cy[3] = ymax;
  bool valid[4];
#pragma unroll
  for (int i = 0; i < 4; ++i)
    valid[i] = (cx[i] >= xmin - tol) && (cx[i] <= xmax + tol) &&
               (cy[i] >= ymin - tol) && (cy[i] <= ymax + tol);
#pragma unroll
  for (int i = 0; i < 4; ++i)
    if (!valid[i]) { cx[i] = xmin - 10000.0f; cy[i] = ymin - 10000.0f; }
  int pk0 = -1, pk1 = -1;
#pragma unroll
  for (int i = 0; i < 4; ++i)
    if (valid[i]) { if (pk0 < 0) pk0 = i; else if (pk1 < 0) pk1 = i; }
#pragma unroll
  for (int i = 0; i < 4; ++i)
    if (!valid[i]) { if (pk0 < 0) pk0 = i; else if (pk1 < 0) pk1 = i; }
  // endpoints in destination-pixel coords: x=(px-1.5)*0.25
  const float x0p = (cx[pk0] - 1.5f) * 0.25f;
  const float y0p = (cy[pk0] - 1.5f) * 0.25f;
  const float pdx = (cx[pk1] - 1.5f) * 0.25f - x0p;
  const float pdy = (cy[pk1] - 1.5f) * 0.25f - y0p;
  const float dx = pdx * (1.0f / 31.0f);
  const float dy = pdy * (1.0f / 31.0f);

  const _Float16* f2b = f2t + (size_t)n * HW * C + cb;

  float m = -1e30f, l = 0.f;
  half2v acc2[4];
#pragma unroll
  for (int i = 0; i < 4; ++i) acc2[i] = (half2v)(_Float16)0;

  // sample at (x,y): loads + packed weights (independent; compiler schedules)
  auto fetch = [&](float x, float y, uint4& A, uint4& B, uint4& Cc, uint4& D,
                   half2v& wa, half2v& wb, half2v& wc, half2v& wd) {
    const float xf = floorf(x), yf = floorf(y);
    const float wx = x - xf, wy = y - yf;
    const int x0 = (int)xf, y0 = (int)yf;
    const bool bx0 = ((unsigned)x0 < W), bx1 = ((unsigned)(x0 + 1) < W);
    const bool by0 = ((unsigned)y0 < H), by1 = ((unsigned)(y0 + 1) < H);
    const int xc0 = min(max(x0, 0), W - 1);
    const int xc1 = min(max(x0 + 1, 0), W - 1);
    const int yc0 = min(max(y0, 0), H - 1);
    const int yc1 = min(max(y0 + 1, 0), H - 1);
    // masked factors (cndmask) instead of bool->float converts
    const float ux0 = bx0 ? (1.f - wx) : 0.f;
    const float ux1 = bx1 ? wx : 0.f;
    const float vy0 = by0 ? (1.f - wy) : 0.f;
    const float vy1 = by1 ? wy : 0.f;
    wa = pk2(vy0 * ux0);
    wb = pk2(vy0 * ux1);
    wc = pk2(vy1 * ux0);
    wd = pk2(vy1 * ux1);
    const int r0 = yc0 * W, r1 = yc1 * W;
    A  = *(const uint4*)(f2b + (r0 + xc0) * C);
    B  = *(const uint4*)(f2b + (r0 + xc1) * C);
    Cc = *(const uint4*)(f2b + (r1 + xc0) * C);
    D  = *(const uint4*)(f2b + (r1 + xc1) * C);
  };

  auto bilin = [&](const uint4& A, const uint4& B, const uint4& Cc,
                   const uint4& D, half2v wa, half2v wb, half2v wc, half2v wd,
                   half2v q[4], float& part) {
    const uint* ap = (const uint*)&A;
    const uint* bp = (const uint*)&B;
    const uint* cp = (const uint*)&Cc;
    const uint* dp = (const uint*)&D;
    part = 0.f;
#pragma unroll
    for (int j = 0; j < 4; ++j) {
      half2v qa = __builtin_bit_cast(half2v, ap[j]) * wa;
      qa += __builtin_bit_cast(half2v, bp[j]) * wb;
      qa += __builtin_bit_cast(half2v, cp[j]) * wc;
      qa += __builtin_bit_cast(half2v, dp[j]) * wd;
      q[j] = qa;
      part = fdot2(qa, f1h[j], part);
    }
  };

  // pairwise plain loop: 2 independent samples per iteration, joint softmax
  float xs = x0p, ys = y0p;
#pragma unroll
  for (int s = 0; s < SS; s += 2) {
    uint4 A0, B0, C0, D0, A1, B1, C1, D1;
    half2v wa0, wb0, wc0, wd0, wa1, wb1, wc1, wd1;
    fetch(xs,      ys,      A0, B0, C0, D0, wa0, wb0, wc0, wd0);
    fetch(xs + dx, ys + dy, A1, B1, C1, D1, wa1, wb1, wc1, wd1);
    xs += 2.f * dx;
    ys += 2.f * dy;

    half2v q0[4], q1[4];
    float p0, p1;
    bilin(A0, B0, C0, D0, wa0, wb0, wc0, wd0, q0, p0);
    bilin(A1, B1, C1, D1, wa1, wb1, wc1, wd1, q1, p1);
    p0 = groupsum32(p0);
    p1 = groupsum32(p1);

    const float mx = fmaxf(p0, p1);
    if (__any(mx > m + 4.f)) {            // defer-max (T=4), joint for pair
      const float mn = fmaxf(m, mx);
      const float sc = __expf(m - mn);
      l *= sc;
      const half2v sch = pk2(sc);
#pragma unroll
      for (int i = 0; i < 4; ++i) acc2[i] *= sch;
      m = mn;
    }
    const float e0 = __expf(p0 - m);
    const float e1 = __expf(p1 - m);
    l += e0 + e1;
    const half2v eh0 = pk2(e0);
    const half2v eh1 = pk2(e1);
#pragma unroll
    for (int i = 0; i < 4; ++i) {
      acc2[i] += eh0 * q0[i];             // v_pk_fma_f16
      acc2[i] += eh1 * q1[i];
    }
  }

  const float inv = 1.0f / l;
  float* ob = out + (size_t)n * C * HW + (size_t)cb * HW + p;
#pragma unroll
  for (int i = 0; i < 4; ++i) {
    ob[(size_t)(2 * i) * HW]     = (float)acc2[i].x * inv;
    ob[(size_t)(2 * i + 1) * HW] = (float)acc2[i].y * inv;
  }
}

extern "C" void kernel_launch(void* const* d_in, const int* in_sizes, int n_in,
                              void* d_out, int out_size, void* d_ws, size_t ws_size,
                              hipStream_t stream) {
  const float* feat1 = (const float*)d_in[0];
  const float* feat2 = (const float*)d_in[1];
  const float* P1 = (const float*)d_in[2];
  const float* P2 = (const float*)d_in[3];
  float* out = (float*)d_out;

  char* ws = (char*)d_ws;
  _Float16* f2t = (_Float16*)ws;                            // 4 MB @ 0
  double*   Fd  = (double*)(ws + (5u << 20));               // @ 5 MB

  prep_kernel<<<dim3(HW / 32, C / 32, NB), dim3(32, 8), 0, stream>>>(
      feat2, P1, P2, f2t, Fd);
  epi_main<<<NB * HW / 8, 256, 0, stream>>>(feat1, f2t, Fd, out);
}